// Round 7
// baseline (319.018 us; speedup 1.0000x reference)
//
#include <hip/hip_runtime.h>
#include <hip/hip_bf16.h>

#define N_NODES 50000
#define N_EDGES 800000
#define NBUK 512            // col-range buckets
#define BWID 98             // cols per bucket: 512*98 = 50176 >= N
#define BCAP 2048           // entries cap/bucket (mean 1562, +12 sigma)
#define PCHUNK 2048         // edges per partition block (38 KB LDS -> 4 blocks/CU)
#define PBLK 391            // ceil(800000/2048)
#define NVS 32              // vsumcol replicas (atomic de-contention)
#define DIAG_REPS 4         // DIAGNOSTIC ROUND: x4 in-kernel repetition of
                            // k_bucket / k_vbar / k_gather so their true
                            // per-dispatch durations surface in rocprof top-5.
                            // Results scaled by 1/DIAG_REPS (exact pow2).
                            // REVERT TO 1 NEXT ROUND.

typedef __bf16 bf16x8 __attribute__((ext_vector_type(8)));
typedef float f32x4 __attribute__((ext_vector_type(4)));

__device__ __forceinline__ unsigned short f2bf(float f) {
    unsigned int u = __builtin_bit_cast(unsigned int, f);
    u += 0x7fffu + ((u >> 16) & 1u);   // round-to-nearest-even
    return (unsigned short)(u >> 16);
}
__device__ __forceinline__ float bf2f(unsigned short s) {
    return __uint_as_float((unsigned int)s << 16);
}

// async 16B global->LDS (no VGPR result; LDS dest = wave-uniform base + lane*16)
__device__ __forceinline__ void gld_lds16(const void* g, void* lds) {
    __builtin_amdgcn_global_load_lds(
        (const __attribute__((address_space(1))) unsigned int*)g,
        (__attribute__((address_space(3))) unsigned int*)lds, 16, 0, 0);
}

// ---------------- Wvbar prep + workspace zeroing (replaces hipMemsetAsync) ----
__global__ __launch_bounds__(256) void k_wprep(const float* __restrict__ Wv,
                                               const float* __restrict__ bv,
                                               unsigned short* __restrict__ wvbar,
                                               float* __restrict__ bvbar,
                                               int* __restrict__ gcur,
                                               float* __restrict__ vsumr) {
    int idx = blockIdx.x * 256 + threadIdx.x;   // 16 blocks -> 4096, 4 cols each
    int d = idx >> 6;
    int c0 = (idx & 63) * 4;
    const float4* W4 = (const float4*)Wv;
    float4 w0 = W4[((d) * 256 + c0) >> 2];
    float4 w1 = W4[((64 + d) * 256 + c0) >> 2];
    float4 w2 = W4[((128 + d) * 256 + c0) >> 2];
    float4 w3 = W4[((192 + d) * 256 + c0) >> 2];
    ushort4 s;
    s.x = f2bf(0.25f * (w0.x + w1.x + w2.x + w3.x));
    s.y = f2bf(0.25f * (w0.y + w1.y + w2.y + w3.y));
    s.z = f2bf(0.25f * (w0.z + w1.z + w2.z + w3.z));
    s.w = f2bf(0.25f * (w0.w + w1.w + w2.w + w3.w));
    int ks = c0 >> 5;
    int q  = (c0 >> 3) & 3;
    int j0 = c0 & 7;
    int nf = d >> 4;
    int ln = d & 15;
    int base = ((ks * 4 + nf) * 64 + q * 16 + ln) * 8 + j0;
    *(ushort4*)&wvbar[base] = s;
    if (blockIdx.x == 0 && threadIdx.x < 64) {
        int t = threadIdx.x;
        bvbar[t] = 0.25f * (bv[t] + bv[64 + t] + bv[128 + t] + bv[192 + t]);
    }
    if (blockIdx.x == 1) {
        for (int i = threadIdx.x; i < NBUK; i += 256) gcur[i] = 0;
    }
    if (blockIdx.x == 2) {
        for (int i = threadIdx.x; i < NVS * 64; i += 256) vsumr[i] = 0.f;
    }
}

// ---------------- edge partition into 512 col-range buckets (UNCHANGED) -------
__global__ __launch_bounds__(256) void k_part(const int* __restrict__ ei,
                                              const float* __restrict__ ew,
                                              int* __restrict__ gcur,
                                              uint2* __restrict__ bkt)
{
    __shared__ int hist[NBUK];
    __shared__ int s2[256];
    __shared__ int lstart[NBUK];
    __shared__ int lcur[NBUK];
    __shared__ int gbase[NBUK];
    __shared__ unsigned short scol[PCHUNK];
    __shared__ uint2 lent[PCHUNK];
    __shared__ unsigned int ldst[PCHUNK];
    const int t = threadIdx.x;
    const int e0 = blockIdx.x * PCHUNK;
    const int cnt = min(N_EDGES - e0, PCHUNK);

    hist[t] = 0; hist[t + 256] = 0;
    __syncthreads();
    #pragma unroll
    for (int k = 0; k < PCHUNK / 256; ++k) {
        int idx = k * 256 + t;
        int e = e0 + idx;
        if (e < N_EDGES) {
            int c = ei[N_EDGES + e];
            scol[idx] = (unsigned short)c;
            atomicAdd(&hist[c / BWID], 1);
        }
    }
    __syncthreads();
    {
        int b = t;
        if (hist[b]) gbase[b] = b * BCAP + atomicAdd(&gcur[b], hist[b]);
        b = t + 256;
        if (hist[b]) gbase[b] = b * BCAP + atomicAdd(&gcur[b], hist[b]);
    }
    s2[t] = hist[2 * t] + hist[2 * t + 1];
    __syncthreads();
    #pragma unroll
    for (int d = 1; d < 256; d <<= 1) {
        int u = (t >= d) ? s2[t - d] : 0;
        __syncthreads();
        s2[t] += u;
        __syncthreads();
    }
    {
        int b0 = (t > 0) ? s2[t - 1] : 0;
        lstart[2 * t] = b0;
        lstart[2 * t + 1] = b0 + hist[2 * t];
        lcur[2 * t] = b0;
        lcur[2 * t + 1] = b0 + hist[2 * t];
    }
    __syncthreads();
    #pragma unroll
    for (int k = 0; k < PCHUNK / 256; ++k) {
        int idx = k * 256 + t;
        int e = e0 + idx;
        if (e < N_EDGES) {
            int c = (int)scol[idx];
            int b = c / BWID;
            int lp = atomicAdd(&lcur[b], 1);
            uint2 en;
            en.x = ((unsigned int)ei[e] << 16) | (unsigned int)f2bf(ew[e]);
            en.y = (unsigned int)(c - b * BWID);
            lent[lp] = en;
            unsigned int gd = (unsigned int)(gbase[b] + (lp - lstart[b]));
            ldst[lp] = (gd < (unsigned int)((b + 1) * BCAP)) ? gd : 0xFFFFFFFFu;
        }
    }
    __syncthreads();
    for (int j = t; j < cnt; j += 256) {
        unsigned int gd = ldst[j];
        if (gd != 0xFFFFFFFFu) bkt[gd] = lent[j];
    }
}

// ---------------- per-bucket sort — DIAGNOSTIC x4 full-body repetition --------
__global__ __launch_bounds__(256) void k_bucket(const int* __restrict__ gcur,
                                                const uint2* __restrict__ bkt,
                                                int* __restrict__ deg,
                                                int* __restrict__ off,
                                                unsigned int* __restrict__ srt)
{
    __shared__ int hist[128];
    __shared__ int lcur[128];
    __shared__ uint2 ent[BCAP];
    __shared__ unsigned int stg[BCAP];
    const int t = threadIdx.x;
    const int b = blockIdx.x;
    const int cnt = min(gcur[b], BCAP);
    const uint2* base = bkt + (size_t)b * BCAP;
    unsigned int* sb = srt + (size_t)b * BCAP;

    for (int rep = 0; rep < DIAG_REPS; ++rep) {   // idempotent: same outputs each rep
        if (t < 128) hist[t] = 0;
        __syncthreads();
        for (int i = t; i < cnt; i += 256) {
            uint2 en = base[i];
            ent[i] = en;
            atomicAdd(&hist[en.y], 1);
        }
        __syncthreads();
        const int v = (t < 128) ? hist[t] : 0;
        #pragma unroll
        for (int d = 1; d < 128; d <<= 1) {
            int u = (t >= d && t < 128) ? hist[t - d] : 0;
            __syncthreads();
            if (t >= d && t < 128) hist[t] += u;
            __syncthreads();
        }
        if (t < 128) {
            int excl = hist[t] - v;
            lcur[t] = excl;
            if (t < BWID) {
                int col = b * BWID + t;
                if (col < N_NODES) {
                    deg[col] = v;
                    off[col] = b * BCAP + excl;
                }
            }
        }
        __syncthreads();
        for (int i = t; i < cnt; i += 256) {
            uint2 en = ent[i];
            int pos = atomicAdd(&lcur[en.y], 1);
            stg[pos] = en.x;
        }
        __syncthreads();
        for (int i = t; i < cnt; i += 256) sb[i] = stg[i];
        __syncthreads();
    }
}

// ---------------- vbar GEMM — DIAGNOSTIC x4 repetition, acc scaled 0.25 -------
__global__ __launch_bounds__(256) void k_vbar(
    const float* __restrict__ Xs, const unsigned short* __restrict__ wvbar,
    const float* __restrict__ bvbar, const int* __restrict__ deg,
    unsigned short* __restrict__ vbarh, float* __restrict__ vsumr)
{
    __shared__ float lX[64 * 128];
    const int t = threadIdx.x;
    const int w = t >> 6;
    const int l = t & 63;
    const int ln = l & 15;
    const int q = l >> 4;
    const int n0 = blockIdx.x * 64;

    const char* Xc = (const char*)Xs;
    const bf16x8* Wf = (const bf16x8*)wvbar;
    const unsigned int swzl = ((unsigned int)(ln & 7)) << 4;
    const char* lrow = (const char*)&lX[(w * 16 + ln) * 128];

    f32x4 acc[4];
    #pragma unroll
    for (int nf = 0; nf < 4; ++nf) acc[nf] = (f32x4){0.f, 0.f, 0.f, 0.f};

    for (int rep = 0; rep < DIAG_REPS; ++rep) {   // accumulate 4 identical passes
        #pragma unroll
        for (int h = 0; h < 2; ++h) {
            #pragma unroll
            for (int i = 0; i < 8; ++i) {
                int r = w * 16 + i * 2 + (l >> 5);
                int g = n0 + r;
                int gc = (g < N_NODES) ? g : 0;
                unsigned int off = ((unsigned int)((l & 31) * 16))
                                 ^ (((unsigned int)(r & 7)) << 4);
                const void* src = Xc + (size_t)gc * 1024 + (unsigned int)(h * 512) + off;
                gld_lds16(src, &lX[(w * 16 + i * 2) * 128]);
            }
            asm volatile("s_waitcnt vmcnt(0)" ::: "memory");
            __builtin_amdgcn_sched_barrier(0);

            #pragma unroll
            for (int ks2 = 0; ks2 < 4; ++ks2) {
                unsigned int c0 = (unsigned int)(ks2 * 128 + q * 32);
                float4 xa = *(const float4*)(lrow + (c0 ^ swzl));
                float4 xb = *(const float4*)(lrow + ((c0 + 16u) ^ swzl));
                bf16x8 A;
                A[0] = (__bf16)xa.x; A[1] = (__bf16)xa.y;
                A[2] = (__bf16)xa.z; A[3] = (__bf16)xa.w;
                A[4] = (__bf16)xb.x; A[5] = (__bf16)xb.y;
                A[6] = (__bf16)xb.z; A[7] = (__bf16)xb.w;
                int ks = h * 4 + ks2;
                #pragma unroll
                for (int nf = 0; nf < 4; ++nf) {
                    bf16x8 bfr = Wf[(ks * 4 + nf) * 64 + l];
                    acc[nf] = __builtin_amdgcn_mfma_f32_16x16x32_bf16(A, bfr, acc[nf], 0, 0, 0);
                }
            }
            // LDS reads must retire before the next stage overwrites the buffer
            asm volatile("s_waitcnt lgkmcnt(0)" ::: "memory");
            __builtin_amdgcn_sched_barrier(0);
        }
    }
    // scale back: 4 identical passes -> x0.25 (exact power of two)
    #pragma unroll
    for (int nf = 0; nf < 4; ++nf) {
        acc[nf][0] *= 0.25f; acc[nf][1] *= 0.25f;
        acc[nf][2] *= 0.25f; acc[nf][3] *= 0.25f;
    }

    float bvb[4];
    #pragma unroll
    for (int nf = 0; nf < 4; ++nf) bvb[nf] = bvbar[nf * 16 + ln];
    float psum[4] = {0.f, 0.f, 0.f, 0.f};
    #pragma unroll
    for (int r4 = 0; r4 < 4; ++r4) {
        int g = n0 + w * 16 + q * 4 + r4;
        bool ok = g < N_NODES;
        float sc = 0.f;
        if (ok) {
            float dg = (float)deg[g];
            sc = (dg > 0.f) ? __frsqrt_rn(dg) : 0.f;
        }
        #pragma unroll
        for (int nf = 0; nf < 4; ++nf) {
            if (ok) {
                vbarh[g * 64 + nf * 16 + ln] = f2bf((acc[nf][r4] + bvb[nf]) * sc);
                psum[nf] += acc[nf][r4];
            }
        }
    }
    #pragma unroll
    for (int nf = 0; nf < 4; ++nf) {
        float v = psum[nf];
        v += __shfl_xor(v, 16, 64);
        v += __shfl_xor(v, 32, 64);
        psum[nf] = v;
    }
    if (l < 16) {
        int rep = (blockIdx.x * 4 + w) & (NVS - 1);
        #pragma unroll
        for (int nf = 0; nf < 4; ++nf)
            atomicAdd(&vsumr[rep * 64 + nf * 16 + ln], psum[nf]);
    }
}

// ---------------- GCN gather — DIAGNOSTIC x4 loop repetition, scaled 0.25 -----
__global__ __launch_bounds__(256) void k_gather(
    const int* __restrict__ off, const int* __restrict__ deg,
    const unsigned int* __restrict__ srt, const unsigned short* __restrict__ vbarh,
    const float* __restrict__ vsumr, const float* __restrict__ bvbar,
    float* __restrict__ out)
{
    const int t = threadIdx.x;
    const int lane = t & 63;
    const int n = blockIdx.x * 4 + (t >> 6);
    if (n >= N_NODES) return;
    const int e0 = off[n];
    const int dc = deg[n];
    const int e1 = e0 + dc;
    float acc = 0.f;
    for (int rep = 0; rep < DIAG_REPS; ++rep) {
        int e = e0;
        for (; e + 7 < e1; e += 8) {
            unsigned int p0 = srt[e];
            unsigned int p1 = srt[e + 1];
            unsigned int p2 = srt[e + 2];
            unsigned int p3 = srt[e + 3];
            unsigned int p4 = srt[e + 4];
            unsigned int p5 = srt[e + 5];
            unsigned int p6 = srt[e + 6];
            unsigned int p7 = srt[e + 7];
            float a0 = __uint_as_float(p0 << 16) * bf2f(vbarh[(p0 >> 16) * 64 + lane]);
            float a1 = __uint_as_float(p1 << 16) * bf2f(vbarh[(p1 >> 16) * 64 + lane]);
            float a2 = __uint_as_float(p2 << 16) * bf2f(vbarh[(p2 >> 16) * 64 + lane]);
            float a3 = __uint_as_float(p3 << 16) * bf2f(vbarh[(p3 >> 16) * 64 + lane]);
            float a4 = __uint_as_float(p4 << 16) * bf2f(vbarh[(p4 >> 16) * 64 + lane]);
            float a5 = __uint_as_float(p5 << 16) * bf2f(vbarh[(p5 >> 16) * 64 + lane]);
            float a6 = __uint_as_float(p6 << 16) * bf2f(vbarh[(p6 >> 16) * 64 + lane]);
            float a7 = __uint_as_float(p7 << 16) * bf2f(vbarh[(p7 >> 16) * 64 + lane]);
            acc += ((a0 + a1) + (a2 + a3)) + ((a4 + a5) + (a6 + a7));
        }
        for (; e < e1; ++e) {
            unsigned int p = srt[e];
            acc += __uint_as_float(p << 16) * bf2f(vbarh[(p >> 16) * 64 + lane]);
        }
    }
    acc *= 0.25f;   // 4 identical passes
    float dcf = (float)dc;
    float scn = (dcf > 0.f) ? __frsqrt_rn(dcf) : 0.f;
    float vs = 0.f;
    #pragma unroll
    for (int i = 0; i < NVS; ++i) vs += vsumr[i * 64 + lane];
    float aconst = vs * (1.0f / (float)N_NODES) + bvbar[lane];
    out[n * 64 + lane] = acc * scn + aconst;
}

extern "C" void kernel_launch(void* const* d_in, const int* in_sizes, int n_in,
                              void* d_out, int out_size, void* d_ws, size_t ws_size,
                              hipStream_t stream)
{
    const float* Xs = (const float*)d_in[1];   // source_input [N,256]
    const float* Wv = (const float*)d_in[6];   // Wv_w [256,256]
    const float* bv = (const float*)d_in[7];   // Wv_b [256]
    const int*   ei = (const int*)d_in[8];     // edge_index [2,E]
    const float* ew = (const float*)d_in[9];   // edge_weight [E]
    float* out = (float*)d_out;                // [N,64]

    unsigned short* vbarh = (unsigned short*)d_ws;               // 6.4 MB
    uint2* bkt  = (uint2*)(vbarh + (size_t)N_NODES * 64);        // 8.39 MB
    unsigned int* srt = (unsigned int*)(bkt + (size_t)NBUK * BCAP); // 4.19 MB
    unsigned short* wvbar = (unsigned short*)(srt + (size_t)NBUK * BCAP); // 32 KB
    float* bvbar   = (float*)(wvbar + 16384);                    // 64
    float* vsumr   = bvbar + 64;                                 // 32 x 64 replicas
    int*   gcur    = (int*)(vsumr + NVS * 64);                   // 512
    int*   deg     = gcur + NBUK;                                // 50,000
    int*   off     = deg + N_NODES;                              // 50,000

    k_wprep<<<16, 256, 0, stream>>>(Wv, bv, wvbar, bvbar, gcur, vsumr);
    k_part<<<PBLK, 256, 0, stream>>>(ei, ew, gcur, bkt);
    k_bucket<<<NBUK, 256, 0, stream>>>(gcur, bkt, deg, off, srt);
    k_vbar<<<(N_NODES + 63) / 64, 256, 0, stream>>>(Xs, wvbar, bvbar, deg, vbarh, vsumr);
    k_gather<<<(NBUK * BWID) / 4, 256, 0, stream>>>(off, deg, srt, vbarh, vsumr, bvbar, out);
}

// Round 8
// 207.993 us; speedup vs baseline: 1.5338x; 1.5338x over previous
//
#include <hip/hip_runtime.h>
#include <hip/hip_bf16.h>

#define N_NODES 50000
#define N_EDGES 800000
#define NBUK 512            // col-range buckets
#define BWID 98             // cols per bucket: 512*98 = 50176 >= N
#define BCAP 2048           // entries cap/bucket (mean 1562, +12 sigma)
#define PCHUNK 2048         // edges per partition block (38 KB LDS -> 4 blocks/CU)
#define PBLK 391            // ceil(800000/2048)
#define NVS 32              // vsumcol replicas (atomic de-contention)
#define VBLK 782            // k_vbar grid: ceil(50000/64)

typedef __bf16 bf16x8 __attribute__((ext_vector_type(8)));
typedef float f32x4 __attribute__((ext_vector_type(4)));

__device__ __forceinline__ unsigned short f2bf(float f) {
    unsigned int u = __builtin_bit_cast(unsigned int, f);
    u += 0x7fffu + ((u >> 16) & 1u);   // round-to-nearest-even
    return (unsigned short)(u >> 16);
}
__device__ __forceinline__ float bf2f(unsigned short s) {
    return __uint_as_float((unsigned int)s << 16);
}

// async 16B global->LDS (no VGPR result; LDS dest = wave-uniform base + lane*16)
__device__ __forceinline__ void gld_lds16(const void* g, void* lds) {
    __builtin_amdgcn_global_load_lds(
        (const __attribute__((address_space(1))) unsigned int*)g,
        (__attribute__((address_space(3))) unsigned int*)lds, 16, 0, 0);
}

// ---------------- Wvbar prep + workspace zeroing (replaces hipMemsetAsync) ----
__global__ __launch_bounds__(256) void k_wprep(const float* __restrict__ Wv,
                                               const float* __restrict__ bv,
                                               unsigned short* __restrict__ wvbar,
                                               float* __restrict__ bvbar,
                                               int* __restrict__ gcur,
                                               float* __restrict__ vsumr,
                                               int* __restrict__ ticket) {
    int idx = blockIdx.x * 256 + threadIdx.x;   // 16 blocks -> 4096, 4 cols each
    int d = idx >> 6;
    int c0 = (idx & 63) * 4;
    const float4* W4 = (const float4*)Wv;
    float4 w0 = W4[((d) * 256 + c0) >> 2];
    float4 w1 = W4[((64 + d) * 256 + c0) >> 2];
    float4 w2 = W4[((128 + d) * 256 + c0) >> 2];
    float4 w3 = W4[((192 + d) * 256 + c0) >> 2];
    ushort4 s;
    s.x = f2bf(0.25f * (w0.x + w1.x + w2.x + w3.x));
    s.y = f2bf(0.25f * (w0.y + w1.y + w2.y + w3.y));
    s.z = f2bf(0.25f * (w0.z + w1.z + w2.z + w3.z));
    s.w = f2bf(0.25f * (w0.w + w1.w + w2.w + w3.w));
    int ks = c0 >> 5;
    int q  = (c0 >> 3) & 3;
    int j0 = c0 & 7;
    int nf = d >> 4;
    int ln = d & 15;
    int base = ((ks * 4 + nf) * 64 + q * 16 + ln) * 8 + j0;
    *(ushort4*)&wvbar[base] = s;
    if (blockIdx.x == 0 && threadIdx.x < 64) {
        int t = threadIdx.x;
        bvbar[t] = 0.25f * (bv[t] + bv[64 + t] + bv[128 + t] + bv[192 + t]);
    }
    if (blockIdx.x == 1) {
        for (int i = threadIdx.x; i < NBUK; i += 256) gcur[i] = 0;
        if (threadIdx.x == 0) *ticket = 0;
    }
    if (blockIdx.x == 2) {
        for (int i = threadIdx.x; i < NVS * 64; i += 256) vsumr[i] = 0.f;
    }
}

// ---------------- edge partition into 512 col-range buckets (round-6 body) ----
__global__ __launch_bounds__(256) void k_part(const int* __restrict__ ei,
                                              const float* __restrict__ ew,
                                              int* __restrict__ gcur,
                                              uint2* __restrict__ bkt)
{
    __shared__ int hist[NBUK];
    __shared__ int s2[256];
    __shared__ int lstart[NBUK];
    __shared__ int lcur[NBUK];
    __shared__ int gbase[NBUK];
    __shared__ unsigned short scol[PCHUNK];
    __shared__ uint2 lent[PCHUNK];
    __shared__ unsigned int ldst[PCHUNK];
    const int t = threadIdx.x;
    const int e0 = blockIdx.x * PCHUNK;
    const int cnt = min(N_EDGES - e0, PCHUNK);

    hist[t] = 0; hist[t + 256] = 0;
    __syncthreads();
    #pragma unroll
    for (int k = 0; k < PCHUNK / 256; ++k) {
        int idx = k * 256 + t;
        int e = e0 + idx;
        if (e < N_EDGES) {
            int c = ei[N_EDGES + e];
            scol[idx] = (unsigned short)c;
            atomicAdd(&hist[c / BWID], 1);
        }
    }
    __syncthreads();
    {
        int b = t;
        if (hist[b]) gbase[b] = b * BCAP + atomicAdd(&gcur[b], hist[b]);
        b = t + 256;
        if (hist[b]) gbase[b] = b * BCAP + atomicAdd(&gcur[b], hist[b]);
    }
    s2[t] = hist[2 * t] + hist[2 * t + 1];
    __syncthreads();
    #pragma unroll
    for (int d = 1; d < 256; d <<= 1) {
        int u = (t >= d) ? s2[t - d] : 0;
        __syncthreads();
        s2[t] += u;
        __syncthreads();
    }
    {
        int b0 = (t > 0) ? s2[t - 1] : 0;
        lstart[2 * t] = b0;
        lstart[2 * t + 1] = b0 + hist[2 * t];
        lcur[2 * t] = b0;
        lcur[2 * t + 1] = b0 + hist[2 * t];
    }
    __syncthreads();
    #pragma unroll
    for (int k = 0; k < PCHUNK / 256; ++k) {
        int idx = k * 256 + t;
        int e = e0 + idx;
        if (e < N_EDGES) {
            int c = (int)scol[idx];
            int b = c / BWID;
            int lp = atomicAdd(&lcur[b], 1);
            uint2 en;
            en.x = ((unsigned int)ei[e] << 16) | (unsigned int)f2bf(ew[e]);
            en.y = (unsigned int)(c - b * BWID);
            lent[lp] = en;
            unsigned int gd = (unsigned int)(gbase[b] + (lp - lstart[b]));
            ldst[lp] = (gd < (unsigned int)((b + 1) * BCAP)) ? gd : 0xFFFFFFFFu;
        }
    }
    __syncthreads();
    for (int j = t; j < cnt; j += 256) {
        unsigned int gd = ldst[j];
        if (gd != 0xFFFFFFFFu) bkt[gd] = lent[j];
    }
}

// ---------------- per-bucket: deg + off + in-bucket sort (round-6 body) -------
__global__ __launch_bounds__(256) void k_bucket(const int* __restrict__ gcur,
                                                const uint2* __restrict__ bkt,
                                                int* __restrict__ deg,
                                                int* __restrict__ off,
                                                unsigned int* __restrict__ srt)
{
    __shared__ int hist[128];
    __shared__ int lcur[128];
    __shared__ uint2 ent[BCAP];
    __shared__ unsigned int stg[BCAP];
    const int t = threadIdx.x;
    const int b = blockIdx.x;
    if (t < 128) hist[t] = 0;
    __syncthreads();
    const int cnt = min(gcur[b], BCAP);
    const uint2* base = bkt + (size_t)b * BCAP;
    for (int i = t; i < cnt; i += 256) {
        uint2 en = base[i];
        ent[i] = en;
        atomicAdd(&hist[en.y], 1);
    }
    __syncthreads();
    const int v = (t < 128) ? hist[t] : 0;
    #pragma unroll
    for (int d = 1; d < 128; d <<= 1) {
        int u = (t >= d && t < 128) ? hist[t - d] : 0;
        __syncthreads();
        if (t >= d && t < 128) hist[t] += u;
        __syncthreads();
    }
    if (t < 128) {
        int excl = hist[t] - v;
        lcur[t] = excl;
        if (t < BWID) {
            int col = b * BWID + t;
            if (col < N_NODES) {
                deg[col] = v;
                off[col] = b * BCAP + excl;
            }
        }
    }
    __syncthreads();
    for (int i = t; i < cnt; i += 256) {
        uint2 en = ent[i];
        int pos = atomicAdd(&lcur[en.y], 1);
        stg[pos] = en.x;
    }
    __syncthreads();
    unsigned int* sb = srt + (size_t)b * BCAP;
    for (int i = t; i < cnt; i += 256) sb[i] = stg[i];
}

// ---------------- vbar GEMM (round-6 body) + last-block aconst reduction ------
// aconst[d] = (sum over replicas of vsumr)/N + bvbar[d], computed ONCE here so
// k_gather's per-wave prologue collapses from 34 loads to 1.
__global__ __launch_bounds__(256) void k_vbar(
    const float* __restrict__ Xs, const unsigned short* __restrict__ wvbar,
    const float* __restrict__ bvbar, const int* __restrict__ deg,
    unsigned short* __restrict__ vbarh, float* __restrict__ vsumr,
    int* __restrict__ ticket, float* __restrict__ aconst)
{
    __shared__ float lX[64 * 128];
    __shared__ int lastflag;
    const int t = threadIdx.x;
    const int w = t >> 6;
    const int l = t & 63;
    const int ln = l & 15;
    const int q = l >> 4;
    const int n0 = blockIdx.x * 64;

    const char* Xc = (const char*)Xs;
    const bf16x8* Wf = (const bf16x8*)wvbar;
    const unsigned int swzl = ((unsigned int)(ln & 7)) << 4;
    const char* lrow = (const char*)&lX[(w * 16 + ln) * 128];

    f32x4 acc[4];
    #pragma unroll
    for (int nf = 0; nf < 4; ++nf) acc[nf] = (f32x4){0.f, 0.f, 0.f, 0.f};

    #pragma unroll
    for (int h = 0; h < 2; ++h) {
        #pragma unroll
        for (int i = 0; i < 8; ++i) {
            int r = w * 16 + i * 2 + (l >> 5);
            int g = n0 + r;
            int gc = (g < N_NODES) ? g : 0;
            unsigned int off = ((unsigned int)((l & 31) * 16))
                             ^ (((unsigned int)(r & 7)) << 4);
            const void* src = Xc + (size_t)gc * 1024 + (unsigned int)(h * 512) + off;
            gld_lds16(src, &lX[(w * 16 + i * 2) * 128]);
        }
        asm volatile("s_waitcnt vmcnt(0)" ::: "memory");
        __builtin_amdgcn_sched_barrier(0);

        #pragma unroll
        for (int ks2 = 0; ks2 < 4; ++ks2) {
            unsigned int c0 = (unsigned int)(ks2 * 128 + q * 32);
            float4 xa = *(const float4*)(lrow + (c0 ^ swzl));
            float4 xb = *(const float4*)(lrow + ((c0 + 16u) ^ swzl));
            bf16x8 A;
            A[0] = (__bf16)xa.x; A[1] = (__bf16)xa.y;
            A[2] = (__bf16)xa.z; A[3] = (__bf16)xa.w;
            A[4] = (__bf16)xb.x; A[5] = (__bf16)xb.y;
            A[6] = (__bf16)xb.z; A[7] = (__bf16)xb.w;
            int ks = h * 4 + ks2;
            #pragma unroll
            for (int nf = 0; nf < 4; ++nf) {
                bf16x8 b = Wf[(ks * 4 + nf) * 64 + l];
                acc[nf] = __builtin_amdgcn_mfma_f32_16x16x32_bf16(A, b, acc[nf], 0, 0, 0);
            }
        }
        if (h == 0) {
            asm volatile("s_waitcnt lgkmcnt(0)" ::: "memory");
            __builtin_amdgcn_sched_barrier(0);
        }
    }

    float bvb[4];
    #pragma unroll
    for (int nf = 0; nf < 4; ++nf) bvb[nf] = bvbar[nf * 16 + ln];
    float psum[4] = {0.f, 0.f, 0.f, 0.f};
    #pragma unroll
    for (int r4 = 0; r4 < 4; ++r4) {
        int g = n0 + w * 16 + q * 4 + r4;
        bool ok = g < N_NODES;
        float sc = 0.f;
        if (ok) {
            float dg = (float)deg[g];
            sc = (dg > 0.f) ? __frsqrt_rn(dg) : 0.f;
        }
        #pragma unroll
        for (int nf = 0; nf < 4; ++nf) {
            if (ok) {
                vbarh[g * 64 + nf * 16 + ln] = f2bf((acc[nf][r4] + bvb[nf]) * sc);
                psum[nf] += acc[nf][r4];
            }
        }
    }
    #pragma unroll
    for (int nf = 0; nf < 4; ++nf) {
        float v = psum[nf];
        v += __shfl_xor(v, 16, 64);
        v += __shfl_xor(v, 32, 64);
        psum[nf] = v;
    }
    if (l < 16) {
        int rep = (blockIdx.x * 4 + w) & (NVS - 1);
        #pragma unroll
        for (int nf = 0; nf < 4; ++nf)
            atomicAdd(&vsumr[rep * 64 + nf * 16 + ln], psum[nf]);
    }
    // ---- last-block aconst reduction (compiler drains vmcnt at the barrier,
    // so this block's atomics are in L2 before the ticket increments) ----
    __syncthreads();
    if (t == 0) {
        int done = atomicAdd(ticket, 1);
        lastflag = (done == (int)gridDim.x - 1) ? 1 : 0;
    }
    __syncthreads();
    if (lastflag) {
        __threadfence();
        if (t < 64) {
            float vs = 0.f;
            #pragma unroll
            for (int i = 0; i < NVS; ++i) vs += vsumr[i * 64 + t];
            aconst[t] = vs * (1.0f / (float)N_NODES) + bvbar[t];
        }
    }
}

// ---------------- GCN gather: 4 nodes per wave, 1-load prologue ---------------
// out[n,d] = aconst[d] + rsqrt(deg[n]) * sum_e w_e * vbarh[row_e, d]
__global__ __launch_bounds__(256) void k_gather(
    const int* __restrict__ off, const int* __restrict__ deg,
    const unsigned int* __restrict__ srt, const unsigned short* __restrict__ vbarh,
    const float* __restrict__ aconst, float* __restrict__ out)
{
    const int t = threadIdx.x;
    const int lane = t & 63;
    const int w = t >> 6;
    const int n0 = blockIdx.x * 16 + w * 4;       // grid: 3136 blocks -> 50176
    const float ac = aconst[lane];
    #pragma unroll
    for (int j = 0; j < 4; ++j) {
        int n = n0 + j;
        if (n >= N_NODES) continue;                // wave-uniform
        const int e0 = off[n];
        const int dc = deg[n];
        const int e1 = e0 + dc;
        float acc = 0.f;
        int e = e0;
        for (; e + 7 < e1; e += 8) {
            unsigned int p0 = srt[e];
            unsigned int p1 = srt[e + 1];
            unsigned int p2 = srt[e + 2];
            unsigned int p3 = srt[e + 3];
            unsigned int p4 = srt[e + 4];
            unsigned int p5 = srt[e + 5];
            unsigned int p6 = srt[e + 6];
            unsigned int p7 = srt[e + 7];
            float a0 = __uint_as_float(p0 << 16) * bf2f(vbarh[(p0 >> 16) * 64 + lane]);
            float a1 = __uint_as_float(p1 << 16) * bf2f(vbarh[(p1 >> 16) * 64 + lane]);
            float a2 = __uint_as_float(p2 << 16) * bf2f(vbarh[(p2 >> 16) * 64 + lane]);
            float a3 = __uint_as_float(p3 << 16) * bf2f(vbarh[(p3 >> 16) * 64 + lane]);
            float a4 = __uint_as_float(p4 << 16) * bf2f(vbarh[(p4 >> 16) * 64 + lane]);
            float a5 = __uint_as_float(p5 << 16) * bf2f(vbarh[(p5 >> 16) * 64 + lane]);
            float a6 = __uint_as_float(p6 << 16) * bf2f(vbarh[(p6 >> 16) * 64 + lane]);
            float a7 = __uint_as_float(p7 << 16) * bf2f(vbarh[(p7 >> 16) * 64 + lane]);
            acc += ((a0 + a1) + (a2 + a3)) + ((a4 + a5) + (a6 + a7));
        }
        for (; e < e1; ++e) {
            unsigned int p = srt[e];
            acc += __uint_as_float(p << 16) * bf2f(vbarh[(p >> 16) * 64 + lane]);
        }
        float dcf = (float)dc;
        float scn = (dcf > 0.f) ? __frsqrt_rn(dcf) : 0.f;
        out[n * 64 + lane] = acc * scn + ac;
    }
}

extern "C" void kernel_launch(void* const* d_in, const int* in_sizes, int n_in,
                              void* d_out, int out_size, void* d_ws, size_t ws_size,
                              hipStream_t stream)
{
    const float* Xs = (const float*)d_in[1];   // source_input [N,256]
    const float* Wv = (const float*)d_in[6];   // Wv_w [256,256]
    const float* bv = (const float*)d_in[7];   // Wv_b [256]
    const int*   ei = (const int*)d_in[8];     // edge_index [2,E]
    const float* ew = (const float*)d_in[9];   // edge_weight [E]
    float* out = (float*)d_out;                // [N,64]

    unsigned short* vbarh = (unsigned short*)d_ws;               // 6.4 MB
    uint2* bkt  = (uint2*)(vbarh + (size_t)N_NODES * 64);        // 8.39 MB
    unsigned int* srt = (unsigned int*)(bkt + (size_t)NBUK * BCAP); // 4.19 MB
    unsigned short* wvbar = (unsigned short*)(srt + (size_t)NBUK * BCAP); // 32 KB
    float* bvbar   = (float*)(wvbar + 16384);                    // 64
    float* vsumr   = bvbar + 64;                                 // 32 x 64 replicas
    float* aconst  = vsumr + NVS * 64;                           // 64
    int*   ticket  = (int*)(aconst + 64);                        // 1
    int*   gcur    = ticket + 1;                                 // 512
    int*   deg     = gcur + NBUK;                                // 50,000
    int*   off     = deg + N_NODES;                              // 50,000

    k_wprep<<<16, 256, 0, stream>>>(Wv, bv, wvbar, bvbar, gcur, vsumr, ticket);
    k_part<<<PBLK, 256, 0, stream>>>(ei, ew, gcur, bkt);
    k_bucket<<<NBUK, 256, 0, stream>>>(gcur, bkt, deg, off, srt);
    k_vbar<<<VBLK, 256, 0, stream>>>(Xs, wvbar, bvbar, deg, vbarh, vsumr, ticket, aconst);
    k_gather<<<3136, 256, 0, stream>>>(off, deg, srt, vbarh, aconst, out);
}

// Round 9
// 201.045 us; speedup vs baseline: 1.5868x; 1.0346x over previous
//
#include <hip/hip_runtime.h>
#include <hip/hip_bf16.h>

#define N_NODES 50000
#define N_EDGES 800000
#define NBUK 512            // col-range buckets
#define BWID 98             // cols per bucket: 512*98 = 50176 >= N
#define BCAP 2048           // entries cap/bucket (mean 1562, +12 sigma)
#define PCHUNK 2048         // edges per partition block (38 KB LDS -> 4 blocks/CU)
#define PBLK 391            // ceil(800000/2048)
#define NVS 32              // vsumcol replicas (atomic de-contention)
#define VBLK 782            // k_vbar grid: ceil(50000/64)

typedef __bf16 bf16x8 __attribute__((ext_vector_type(8)));
typedef float f32x4 __attribute__((ext_vector_type(4)));

__device__ __forceinline__ unsigned short f2bf(float f) {
    unsigned int u = __builtin_bit_cast(unsigned int, f);
    u += 0x7fffu + ((u >> 16) & 1u);   // round-to-nearest-even
    return (unsigned short)(u >> 16);
}
__device__ __forceinline__ float bf2f(unsigned short s) {
    return __uint_as_float((unsigned int)s << 16);
}

// async 16B global->LDS (no VGPR result; LDS dest = wave-uniform base + lane*16)
__device__ __forceinline__ void gld_lds16(const void* g, void* lds) {
    __builtin_amdgcn_global_load_lds(
        (const __attribute__((address_space(1))) unsigned int*)g,
        (__attribute__((address_space(3))) unsigned int*)lds, 16, 0, 0);
}

// ---------------- Wvbar prep + workspace zeroing (replaces hipMemsetAsync) ----
__global__ __launch_bounds__(256) void k_wprep(const float* __restrict__ Wv,
                                               const float* __restrict__ bv,
                                               unsigned short* __restrict__ wvbar,
                                               float* __restrict__ bvbar,
                                               int* __restrict__ gcur,
                                               float* __restrict__ vsumr,
                                               int* __restrict__ ticket) {
    int idx = blockIdx.x * 256 + threadIdx.x;   // 16 blocks -> 4096, 4 cols each
    int d = idx >> 6;
    int c0 = (idx & 63) * 4;
    const float4* W4 = (const float4*)Wv;
    float4 w0 = W4[((d) * 256 + c0) >> 2];
    float4 w1 = W4[((64 + d) * 256 + c0) >> 2];
    float4 w2 = W4[((128 + d) * 256 + c0) >> 2];
    float4 w3 = W4[((192 + d) * 256 + c0) >> 2];
    ushort4 s;
    s.x = f2bf(0.25f * (w0.x + w1.x + w2.x + w3.x));
    s.y = f2bf(0.25f * (w0.y + w1.y + w2.y + w3.y));
    s.z = f2bf(0.25f * (w0.z + w1.z + w2.z + w3.z));
    s.w = f2bf(0.25f * (w0.w + w1.w + w2.w + w3.w));
    int ks = c0 >> 5;
    int q  = (c0 >> 3) & 3;
    int j0 = c0 & 7;
    int nf = d >> 4;
    int ln = d & 15;
    int base = ((ks * 4 + nf) * 64 + q * 16 + ln) * 8 + j0;
    *(ushort4*)&wvbar[base] = s;
    if (blockIdx.x == 0 && threadIdx.x < 64) {
        int t = threadIdx.x;
        bvbar[t] = 0.25f * (bv[t] + bv[64 + t] + bv[128 + t] + bv[192 + t]);
    }
    if (blockIdx.x == 1) {
        for (int i = threadIdx.x; i < NBUK; i += 256) gcur[i] = 0;
        if (threadIdx.x == 0) *ticket = 0;
    }
    if (blockIdx.x == 2) {
        for (int i = threadIdx.x; i < NVS * 64; i += 256) vsumr[i] = 0.f;
    }
}

// ---------------- edge partition into 512 col-range buckets (round-6 body) ----
__global__ __launch_bounds__(256) void k_part(const int* __restrict__ ei,
                                              const float* __restrict__ ew,
                                              int* __restrict__ gcur,
                                              uint2* __restrict__ bkt)
{
    __shared__ int hist[NBUK];
    __shared__ int s2[256];
    __shared__ int lstart[NBUK];
    __shared__ int lcur[NBUK];
    __shared__ int gbase[NBUK];
    __shared__ unsigned short scol[PCHUNK];
    __shared__ uint2 lent[PCHUNK];
    __shared__ unsigned int ldst[PCHUNK];
    const int t = threadIdx.x;
    const int e0 = blockIdx.x * PCHUNK;
    const int cnt = min(N_EDGES - e0, PCHUNK);

    hist[t] = 0; hist[t + 256] = 0;
    __syncthreads();
    #pragma unroll
    for (int k = 0; k < PCHUNK / 256; ++k) {
        int idx = k * 256 + t;
        int e = e0 + idx;
        if (e < N_EDGES) {
            int c = ei[N_EDGES + e];
            scol[idx] = (unsigned short)c;
            atomicAdd(&hist[c / BWID], 1);
        }
    }
    __syncthreads();
    {
        int b = t;
        if (hist[b]) gbase[b] = b * BCAP + atomicAdd(&gcur[b], hist[b]);
        b = t + 256;
        if (hist[b]) gbase[b] = b * BCAP + atomicAdd(&gcur[b], hist[b]);
    }
    s2[t] = hist[2 * t] + hist[2 * t + 1];
    __syncthreads();
    #pragma unroll
    for (int d = 1; d < 256; d <<= 1) {
        int u = (t >= d) ? s2[t - d] : 0;
        __syncthreads();
        s2[t] += u;
        __syncthreads();
    }
    {
        int b0 = (t > 0) ? s2[t - 1] : 0;
        lstart[2 * t] = b0;
        lstart[2 * t + 1] = b0 + hist[2 * t];
        lcur[2 * t] = b0;
        lcur[2 * t + 1] = b0 + hist[2 * t];
    }
    __syncthreads();
    #pragma unroll
    for (int k = 0; k < PCHUNK / 256; ++k) {
        int idx = k * 256 + t;
        int e = e0 + idx;
        if (e < N_EDGES) {
            int c = (int)scol[idx];
            int b = c / BWID;
            int lp = atomicAdd(&lcur[b], 1);
            uint2 en;
            en.x = ((unsigned int)ei[e] << 16) | (unsigned int)f2bf(ew[e]);
            en.y = (unsigned int)(c - b * BWID);
            lent[lp] = en;
            unsigned int gd = (unsigned int)(gbase[b] + (lp - lstart[b]));
            ldst[lp] = (gd < (unsigned int)((b + 1) * BCAP)) ? gd : 0xFFFFFFFFu;
        }
    }
    __syncthreads();
    for (int j = t; j < cnt; j += 256) {
        unsigned int gd = ldst[j];
        if (gd != 0xFFFFFFFFu) bkt[gd] = lent[j];
    }
}

// ---------------- per-bucket: deg + off + in-bucket sort (round-6 body) -------
__global__ __launch_bounds__(256) void k_bucket(const int* __restrict__ gcur,
                                                const uint2* __restrict__ bkt,
                                                int* __restrict__ deg,
                                                int* __restrict__ off,
                                                unsigned int* __restrict__ srt)
{
    __shared__ int hist[128];
    __shared__ int lcur[128];
    __shared__ uint2 ent[BCAP];
    __shared__ unsigned int stg[BCAP];
    const int t = threadIdx.x;
    const int b = blockIdx.x;
    if (t < 128) hist[t] = 0;
    __syncthreads();
    const int cnt = min(gcur[b], BCAP);
    const uint2* base = bkt + (size_t)b * BCAP;
    for (int i = t; i < cnt; i += 256) {
        uint2 en = base[i];
        ent[i] = en;
        atomicAdd(&hist[en.y], 1);
    }
    __syncthreads();
    const int v = (t < 128) ? hist[t] : 0;
    #pragma unroll
    for (int d = 1; d < 128; d <<= 1) {
        int u = (t >= d && t < 128) ? hist[t - d] : 0;
        __syncthreads();
        if (t >= d && t < 128) hist[t] += u;
        __syncthreads();
    }
    if (t < 128) {
        int excl = hist[t] - v;
        lcur[t] = excl;
        if (t < BWID) {
            int col = b * BWID + t;
            if (col < N_NODES) {
                deg[col] = v;
                off[col] = b * BCAP + excl;
            }
        }
    }
    __syncthreads();
    for (int i = t; i < cnt; i += 256) {
        uint2 en = ent[i];
        int pos = atomicAdd(&lcur[en.y], 1);
        stg[pos] = en.x;
    }
    __syncthreads();
    unsigned int* sb = srt + (size_t)b * BCAP;
    for (int i = t; i < cnt; i += 256) sb[i] = stg[i];
}

// ---------------- vbar GEMM (round-6 body) + last-block aconst reduction ------
// aconst[d] = (sum over replicas of vsumr)/N + bvbar[d], computed ONCE here so
// k_gather's per-wave prologue collapses from 34 loads to 1.
__global__ __launch_bounds__(256) void k_vbar(
    const float* __restrict__ Xs, const unsigned short* __restrict__ wvbar,
    const float* __restrict__ bvbar, const int* __restrict__ deg,
    unsigned short* __restrict__ vbarh, float* __restrict__ vsumr,
    int* __restrict__ ticket, float* __restrict__ aconst)
{
    __shared__ float lX[64 * 128];
    __shared__ int lastflag;
    const int t = threadIdx.x;
    const int w = t >> 6;
    const int l = t & 63;
    const int ln = l & 15;
    const int q = l >> 4;
    const int n0 = blockIdx.x * 64;

    const char* Xc = (const char*)Xs;
    const bf16x8* Wf = (const bf16x8*)wvbar;
    const unsigned int swzl = ((unsigned int)(ln & 7)) << 4;
    const char* lrow = (const char*)&lX[(w * 16 + ln) * 128];

    f32x4 acc[4];
    #pragma unroll
    for (int nf = 0; nf < 4; ++nf) acc[nf] = (f32x4){0.f, 0.f, 0.f, 0.f};

    #pragma unroll
    for (int h = 0; h < 2; ++h) {
        #pragma unroll
        for (int i = 0; i < 8; ++i) {
            int r = w * 16 + i * 2 + (l >> 5);
            int g = n0 + r;
            int gc = (g < N_NODES) ? g : 0;
            unsigned int off = ((unsigned int)((l & 31) * 16))
                             ^ (((unsigned int)(r & 7)) << 4);
            const void* src = Xc + (size_t)gc * 1024 + (unsigned int)(h * 512) + off;
            gld_lds16(src, &lX[(w * 16 + i * 2) * 128]);
        }
        asm volatile("s_waitcnt vmcnt(0)" ::: "memory");
        __builtin_amdgcn_sched_barrier(0);

        #pragma unroll
        for (int ks2 = 0; ks2 < 4; ++ks2) {
            unsigned int c0 = (unsigned int)(ks2 * 128 + q * 32);
            float4 xa = *(const float4*)(lrow + (c0 ^ swzl));
            float4 xb = *(const float4*)(lrow + ((c0 + 16u) ^ swzl));
            bf16x8 A;
            A[0] = (__bf16)xa.x; A[1] = (__bf16)xa.y;
            A[2] = (__bf16)xa.z; A[3] = (__bf16)xa.w;
            A[4] = (__bf16)xb.x; A[5] = (__bf16)xb.y;
            A[6] = (__bf16)xb.z; A[7] = (__bf16)xb.w;
            int ks = h * 4 + ks2;
            #pragma unroll
            for (int nf = 0; nf < 4; ++nf) {
                bf16x8 b = Wf[(ks * 4 + nf) * 64 + l];
                acc[nf] = __builtin_amdgcn_mfma_f32_16x16x32_bf16(A, b, acc[nf], 0, 0, 0);
            }
        }
        if (h == 0) {
            asm volatile("s_waitcnt lgkmcnt(0)" ::: "memory");
            __builtin_amdgcn_sched_barrier(0);
        }
    }

    float bvb[4];
    #pragma unroll
    for (int nf = 0; nf < 4; ++nf) bvb[nf] = bvbar[nf * 16 + ln];
    float psum[4] = {0.f, 0.f, 0.f, 0.f};
    #pragma unroll
    for (int r4 = 0; r4 < 4; ++r4) {
        int g = n0 + w * 16 + q * 4 + r4;
        bool ok = g < N_NODES;
        float sc = 0.f;
        if (ok) {
            float dg = (float)deg[g];
            sc = (dg > 0.f) ? __frsqrt_rn(dg) : 0.f;
        }
        #pragma unroll
        for (int nf = 0; nf < 4; ++nf) {
            if (ok) {
                vbarh[g * 64 + nf * 16 + ln] = f2bf((acc[nf][r4] + bvb[nf]) * sc);
                psum[nf] += acc[nf][r4];
            }
        }
    }
    #pragma unroll
    for (int nf = 0; nf < 4; ++nf) {
        float v = psum[nf];
        v += __shfl_xor(v, 16, 64);
        v += __shfl_xor(v, 32, 64);
        psum[nf] = v;
    }
    if (l < 16) {
        int rep = (blockIdx.x * 4 + w) & (NVS - 1);
        #pragma unroll
        for (int nf = 0; nf < 4; ++nf)
            atomicAdd(&vsumr[rep * 64 + nf * 16 + ln], psum[nf]);
    }
    // ---- last-block aconst reduction (barrier drains this block's atomics) ----
    __syncthreads();
    if (t == 0) {
        int done = atomicAdd(ticket, 1);
        lastflag = (done == (int)gridDim.x - 1) ? 1 : 0;
    }
    __syncthreads();
    if (lastflag) {
        __threadfence();
        if (t < 64) {
            float vs = 0.f;
            #pragma unroll
            for (int i = 0; i < NVS; ++i) vs += vsumr[i * 64 + t];
            aconst[t] = vs * (1.0f / (float)N_NODES) + bvbar[t];
        }
    }
}

// ---------------- GCN gather: ONE node per wave (max TLP), 1-load prologue ----
// out[n,d] = aconst[d] + rsqrt(deg[n]) * sum_e w_e * vbarh[row_e, d]
__global__ __launch_bounds__(256) void k_gather(
    const int* __restrict__ off, const int* __restrict__ deg,
    const unsigned int* __restrict__ srt, const unsigned short* __restrict__ vbarh,
    const float* __restrict__ aconst, float* __restrict__ out)
{
    const int t = threadIdx.x;
    const int lane = t & 63;
    const int n = blockIdx.x * 4 + (t >> 6);          // grid: 12544 blocks -> 50176
    if (n >= N_NODES) return;                          // whole wave exits together
    const float ac = aconst[lane];                     // L2-hot broadcast, 1 load
    const int e0 = off[n];
    const int dc = deg[n];
    const int e1 = e0 + dc;
    float acc = 0.f;
    int e = e0;
    for (; e + 7 < e1; e += 8) {                       // avg deg 16 -> ~2 rounds
        unsigned int p0 = srt[e];
        unsigned int p1 = srt[e + 1];
        unsigned int p2 = srt[e + 2];
        unsigned int p3 = srt[e + 3];
        unsigned int p4 = srt[e + 4];
        unsigned int p5 = srt[e + 5];
        unsigned int p6 = srt[e + 6];
        unsigned int p7 = srt[e + 7];
        float a0 = __uint_as_float(p0 << 16) * bf2f(vbarh[(p0 >> 16) * 64 + lane]);
        float a1 = __uint_as_float(p1 << 16) * bf2f(vbarh[(p1 >> 16) * 64 + lane]);
        float a2 = __uint_as_float(p2 << 16) * bf2f(vbarh[(p2 >> 16) * 64 + lane]);
        float a3 = __uint_as_float(p3 << 16) * bf2f(vbarh[(p3 >> 16) * 64 + lane]);
        float a4 = __uint_as_float(p4 << 16) * bf2f(vbarh[(p4 >> 16) * 64 + lane]);
        float a5 = __uint_as_float(p5 << 16) * bf2f(vbarh[(p5 >> 16) * 64 + lane]);
        float a6 = __uint_as_float(p6 << 16) * bf2f(vbarh[(p6 >> 16) * 64 + lane]);
        float a7 = __uint_as_float(p7 << 16) * bf2f(vbarh[(p7 >> 16) * 64 + lane]);
        acc += ((a0 + a1) + (a2 + a3)) + ((a4 + a5) + (a6 + a7));
    }
    for (; e < e1; ++e) {
        unsigned int p = srt[e];
        acc += __uint_as_float(p << 16) * bf2f(vbarh[(p >> 16) * 64 + lane]);
    }
    float dcf = (float)dc;
    float scn = (dcf > 0.f) ? __frsqrt_rn(dcf) : 0.f;
    out[n * 64 + lane] = acc * scn + ac;
}

extern "C" void kernel_launch(void* const* d_in, const int* in_sizes, int n_in,
                              void* d_out, int out_size, void* d_ws, size_t ws_size,
                              hipStream_t stream)
{
    const float* Xs = (const float*)d_in[1];   // source_input [N,256]
    const float* Wv = (const float*)d_in[6];   // Wv_w [256,256]
    const float* bv = (const float*)d_in[7];   // Wv_b [256]
    const int*   ei = (const int*)d_in[8];     // edge_index [2,E]
    const float* ew = (const float*)d_in[9];   // edge_weight [E]
    float* out = (float*)d_out;                // [N,64]

    unsigned short* vbarh = (unsigned short*)d_ws;               // 6.4 MB
    uint2* bkt  = (uint2*)(vbarh + (size_t)N_NODES * 64);        // 8.39 MB
    unsigned int* srt = (unsigned int*)(bkt + (size_t)NBUK * BCAP); // 4.19 MB
    unsigned short* wvbar = (unsigned short*)(srt + (size_t)NBUK * BCAP); // 32 KB
    float* bvbar   = (float*)(wvbar + 16384);                    // 64
    float* vsumr   = bvbar + 64;                                 // 32 x 64 replicas
    float* aconst  = vsumr + NVS * 64;                           // 64
    int*   ticket  = (int*)(aconst + 64);                        // 1
    int*   gcur    = ticket + 1;                                 // 512
    int*   deg     = gcur + NBUK;                                // 50,000
    int*   off     = deg + N_NODES;                              // 50,000

    k_wprep<<<16, 256, 0, stream>>>(Wv, bv, wvbar, bvbar, gcur, vsumr, ticket);
    k_part<<<PBLK, 256, 0, stream>>>(ei, ew, gcur, bkt);
    k_bucket<<<NBUK, 256, 0, stream>>>(gcur, bkt, deg, off, srt);
    k_vbar<<<VBLK, 256, 0, stream>>>(Xs, wvbar, bvbar, deg, vbarh, vsumr, ticket, aconst);
    k_gather<<<12544, 256, 0, stream>>>(off, deg, srt, vbarh, aconst, out);
}

// Round 10
// 193.699 us; speedup vs baseline: 1.6470x; 1.0379x over previous
//
#include <hip/hip_runtime.h>
#include <hip/hip_bf16.h>

#define N_NODES 50000
#define N_EDGES 800000
#define NBUK 512            // col-range buckets
#define BWID 98             // cols per bucket: 512*98 = 50176 >= N
#define BCAP 2048           // entries cap/bucket (mean 1562, +12 sigma)
#define PCHUNK 2048         // edges per partition block (38 KB LDS -> 4 blocks/CU)
#define PBLK 391            // ceil(800000/2048)
#define NVS 32              // vsumcol replicas (atomic de-contention)
#define VBLK 782            // k_vbar grid: ceil(50000/64)

typedef __bf16 bf16x8 __attribute__((ext_vector_type(8)));
typedef float f32x4 __attribute__((ext_vector_type(4)));

__device__ __forceinline__ unsigned short f2bf(float f) {
    unsigned int u = __builtin_bit_cast(unsigned int, f);
    u += 0x7fffu + ((u >> 16) & 1u);   // round-to-nearest-even
    return (unsigned short)(u >> 16);
}
__device__ __forceinline__ float bf2f(unsigned short s) {
    return __uint_as_float((unsigned int)s << 16);
}

// async 16B global->LDS (no VGPR result; LDS dest = wave-uniform base + lane*16)
__device__ __forceinline__ void gld_lds16(const void* g, void* lds) {
    __builtin_amdgcn_global_load_lds(
        (const __attribute__((address_space(1))) unsigned int*)g,
        (__attribute__((address_space(3))) unsigned int*)lds, 16, 0, 0);
}

// ---------------- Wvbar prep + workspace zeroing (replaces hipMemsetAsync) ----
__global__ __launch_bounds__(256) void k_wprep(const float* __restrict__ Wv,
                                               const float* __restrict__ bv,
                                               unsigned short* __restrict__ wvbar,
                                               float* __restrict__ bvbar,
                                               int* __restrict__ gcur,
                                               float* __restrict__ vsumr,
                                               int* __restrict__ ticket) {
    int idx = blockIdx.x * 256 + threadIdx.x;   // 16 blocks -> 4096, 4 cols each
    int d = idx >> 6;
    int c0 = (idx & 63) * 4;
    const float4* W4 = (const float4*)Wv;
    float4 w0 = W4[((d) * 256 + c0) >> 2];
    float4 w1 = W4[((64 + d) * 256 + c0) >> 2];
    float4 w2 = W4[((128 + d) * 256 + c0) >> 2];
    float4 w3 = W4[((192 + d) * 256 + c0) >> 2];
    ushort4 s;
    s.x = f2bf(0.25f * (w0.x + w1.x + w2.x + w3.x));
    s.y = f2bf(0.25f * (w0.y + w1.y + w2.y + w3.y));
    s.z = f2bf(0.25f * (w0.z + w1.z + w2.z + w3.z));
    s.w = f2bf(0.25f * (w0.w + w1.w + w2.w + w3.w));
    int ks = c0 >> 5;
    int q  = (c0 >> 3) & 3;
    int j0 = c0 & 7;
    int nf = d >> 4;
    int ln = d & 15;
    int base = ((ks * 4 + nf) * 64 + q * 16 + ln) * 8 + j0;
    *(ushort4*)&wvbar[base] = s;
    if (blockIdx.x == 0 && threadIdx.x < 64) {
        int t = threadIdx.x;
        bvbar[t] = 0.25f * (bv[t] + bv[64 + t] + bv[128 + t] + bv[192 + t]);
    }
    if (blockIdx.x == 1) {
        for (int i = threadIdx.x; i < NBUK; i += 256) gcur[i] = 0;
        if (threadIdx.x == 0) *ticket = 0;
    }
    if (blockIdx.x == 2) {
        for (int i = threadIdx.x; i < NVS * 64; i += 256) vsumr[i] = 0.f;
    }
}

// ---------------- edge partition into 512 col-range buckets (round-6 body) ----
__global__ __launch_bounds__(256) void k_part(const int* __restrict__ ei,
                                              const float* __restrict__ ew,
                                              int* __restrict__ gcur,
                                              uint2* __restrict__ bkt)
{
    __shared__ int hist[NBUK];
    __shared__ int s2[256];
    __shared__ int lstart[NBUK];
    __shared__ int lcur[NBUK];
    __shared__ int gbase[NBUK];
    __shared__ unsigned short scol[PCHUNK];
    __shared__ uint2 lent[PCHUNK];
    __shared__ unsigned int ldst[PCHUNK];
    const int t = threadIdx.x;
    const int e0 = blockIdx.x * PCHUNK;
    const int cnt = min(N_EDGES - e0, PCHUNK);

    hist[t] = 0; hist[t + 256] = 0;
    __syncthreads();
    #pragma unroll
    for (int k = 0; k < PCHUNK / 256; ++k) {
        int idx = k * 256 + t;
        int e = e0 + idx;
        if (e < N_EDGES) {
            int c = ei[N_EDGES + e];
            scol[idx] = (unsigned short)c;
            atomicAdd(&hist[c / BWID], 1);
        }
    }
    __syncthreads();
    {
        int b = t;
        if (hist[b]) gbase[b] = b * BCAP + atomicAdd(&gcur[b], hist[b]);
        b = t + 256;
        if (hist[b]) gbase[b] = b * BCAP + atomicAdd(&gcur[b], hist[b]);
    }
    s2[t] = hist[2 * t] + hist[2 * t + 1];
    __syncthreads();
    #pragma unroll
    for (int d = 1; d < 256; d <<= 1) {
        int u = (t >= d) ? s2[t - d] : 0;
        __syncthreads();
        s2[t] += u;
        __syncthreads();
    }
    {
        int b0 = (t > 0) ? s2[t - 1] : 0;
        lstart[2 * t] = b0;
        lstart[2 * t + 1] = b0 + hist[2 * t];
        lcur[2 * t] = b0;
        lcur[2 * t + 1] = b0 + hist[2 * t];
    }
    __syncthreads();
    #pragma unroll
    for (int k = 0; k < PCHUNK / 256; ++k) {
        int idx = k * 256 + t;
        int e = e0 + idx;
        if (e < N_EDGES) {
            int c = (int)scol[idx];
            int b = c / BWID;
            int lp = atomicAdd(&lcur[b], 1);
            uint2 en;
            en.x = ((unsigned int)ei[e] << 16) | (unsigned int)f2bf(ew[e]);
            en.y = (unsigned int)(c - b * BWID);
            lent[lp] = en;
            unsigned int gd = (unsigned int)(gbase[b] + (lp - lstart[b]));
            ldst[lp] = (gd < (unsigned int)((b + 1) * BCAP)) ? gd : 0xFFFFFFFFu;
        }
    }
    __syncthreads();
    for (int j = t; j < cnt; j += 256) {
        unsigned int gd = ldst[j];
        if (gd != 0xFFFFFFFFu) bkt[gd] = lent[j];
    }
}

// ---------------- per-bucket: deg + off + in-bucket sort (round-6 body) -------
__global__ __launch_bounds__(256) void k_bucket(const int* __restrict__ gcur,
                                                const uint2* __restrict__ bkt,
                                                int* __restrict__ deg,
                                                int* __restrict__ off,
                                                unsigned int* __restrict__ srt)
{
    __shared__ int hist[128];
    __shared__ int lcur[128];
    __shared__ uint2 ent[BCAP];
    __shared__ unsigned int stg[BCAP];
    const int t = threadIdx.x;
    const int b = blockIdx.x;
    if (t < 128) hist[t] = 0;
    __syncthreads();
    const int cnt = min(gcur[b], BCAP);
    const uint2* base = bkt + (size_t)b * BCAP;
    for (int i = t; i < cnt; i += 256) {
        uint2 en = base[i];
        ent[i] = en;
        atomicAdd(&hist[en.y], 1);
    }
    __syncthreads();
    const int v = (t < 128) ? hist[t] : 0;
    #pragma unroll
    for (int d = 1; d < 128; d <<= 1) {
        int u = (t >= d && t < 128) ? hist[t - d] : 0;
        __syncthreads();
        if (t >= d && t < 128) hist[t] += u;
        __syncthreads();
    }
    if (t < 128) {
        int excl = hist[t] - v;
        lcur[t] = excl;
        if (t < BWID) {
            int col = b * BWID + t;
            if (col < N_NODES) {
                deg[col] = v;
                off[col] = b * BCAP + excl;
            }
        }
    }
    __syncthreads();
    for (int i = t; i < cnt; i += 256) {
        uint2 en = ent[i];
        int pos = atomicAdd(&lcur[en.y], 1);
        stg[pos] = en.x;
    }
    __syncthreads();
    unsigned int* sb = srt + (size_t)b * BCAP;
    for (int i = t; i < cnt; i += 256) sb[i] = stg[i];
}

// ---------------- vbar GEMM (round-6 body) + last-block aconst reduction ------
__global__ __launch_bounds__(256) void k_vbar(
    const float* __restrict__ Xs, const unsigned short* __restrict__ wvbar,
    const float* __restrict__ bvbar, const int* __restrict__ deg,
    unsigned short* __restrict__ vbarh, float* __restrict__ vsumr,
    int* __restrict__ ticket, float* __restrict__ aconst)
{
    __shared__ float lX[64 * 128];
    __shared__ int lastflag;
    const int t = threadIdx.x;
    const int w = t >> 6;
    const int l = t & 63;
    const int ln = l & 15;
    const int q = l >> 4;
    const int n0 = blockIdx.x * 64;

    const char* Xc = (const char*)Xs;
    const bf16x8* Wf = (const bf16x8*)wvbar;
    const unsigned int swzl = ((unsigned int)(ln & 7)) << 4;
    const char* lrow = (const char*)&lX[(w * 16 + ln) * 128];

    f32x4 acc[4];
    #pragma unroll
    for (int nf = 0; nf < 4; ++nf) acc[nf] = (f32x4){0.f, 0.f, 0.f, 0.f};

    #pragma unroll
    for (int h = 0; h < 2; ++h) {
        #pragma unroll
        for (int i = 0; i < 8; ++i) {
            int r = w * 16 + i * 2 + (l >> 5);
            int g = n0 + r;
            int gc = (g < N_NODES) ? g : 0;
            unsigned int off = ((unsigned int)((l & 31) * 16))
                             ^ (((unsigned int)(r & 7)) << 4);
            const void* src = Xc + (size_t)gc * 1024 + (unsigned int)(h * 512) + off;
            gld_lds16(src, &lX[(w * 16 + i * 2) * 128]);
        }
        asm volatile("s_waitcnt vmcnt(0)" ::: "memory");
        __builtin_amdgcn_sched_barrier(0);

        #pragma unroll
        for (int ks2 = 0; ks2 < 4; ++ks2) {
            unsigned int c0 = (unsigned int)(ks2 * 128 + q * 32);
            float4 xa = *(const float4*)(lrow + (c0 ^ swzl));
            float4 xb = *(const float4*)(lrow + ((c0 + 16u) ^ swzl));
            bf16x8 A;
            A[0] = (__bf16)xa.x; A[1] = (__bf16)xa.y;
            A[2] = (__bf16)xa.z; A[3] = (__bf16)xa.w;
            A[4] = (__bf16)xb.x; A[5] = (__bf16)xb.y;
            A[6] = (__bf16)xb.z; A[7] = (__bf16)xb.w;
            int ks = h * 4 + ks2;
            #pragma unroll
            for (int nf = 0; nf < 4; ++nf) {
                bf16x8 b = Wf[(ks * 4 + nf) * 64 + l];
                acc[nf] = __builtin_amdgcn_mfma_f32_16x16x32_bf16(A, b, acc[nf], 0, 0, 0);
            }
        }
        if (h == 0) {
            asm volatile("s_waitcnt lgkmcnt(0)" ::: "memory");
            __builtin_amdgcn_sched_barrier(0);
        }
    }

    float bvb[4];
    #pragma unroll
    for (int nf = 0; nf < 4; ++nf) bvb[nf] = bvbar[nf * 16 + ln];
    float psum[4] = {0.f, 0.f, 0.f, 0.f};
    #pragma unroll
    for (int r4 = 0; r4 < 4; ++r4) {
        int g = n0 + w * 16 + q * 4 + r4;
        bool ok = g < N_NODES;
        float sc = 0.f;
        if (ok) {
            float dg = (float)deg[g];
            sc = (dg > 0.f) ? __frsqrt_rn(dg) : 0.f;
        }
        #pragma unroll
        for (int nf = 0; nf < 4; ++nf) {
            if (ok) {
                vbarh[g * 64 + nf * 16 + ln] = f2bf((acc[nf][r4] + bvb[nf]) * sc);
                psum[nf] += acc[nf][r4];
            }
        }
    }
    #pragma unroll
    for (int nf = 0; nf < 4; ++nf) {
        float v = psum[nf];
        v += __shfl_xor(v, 16, 64);
        v += __shfl_xor(v, 32, 64);
        psum[nf] = v;
    }
    if (l < 16) {
        int rep = (blockIdx.x * 4 + w) & (NVS - 1);
        #pragma unroll
        for (int nf = 0; nf < 4; ++nf)
            atomicAdd(&vsumr[rep * 64 + nf * 16 + ln], psum[nf]);
    }
    // ---- last-block aconst reduction (barrier drains this block's atomics) ----
    __syncthreads();
    if (t == 0) {
        int done = atomicAdd(ticket, 1);
        lastflag = (done == (int)gridDim.x - 1) ? 1 : 0;
    }
    __syncthreads();
    if (lastflag) {
        __threadfence();
        if (t < 64) {
            float vs = 0.f;
            #pragma unroll
            for (int i = 0; i < NVS; ++i) vs += vsumr[i * 64 + t];
            aconst[t] = vs * (1.0f / (float)N_NODES) + bvbar[t];
        }
    }
}

// ---------------- GCN gather: split-wave, 2-channel lanes ---------------------
// Low 32 lanes process even edges, high 32 odd edges; each lane covers a
// channel PAIR via one packed uint read of vbarh (2 bf16) + 2 FMAs.
// Per 2 edges per lane: 2 loads + ~9 VALU (was 4 loads + ~14 VALU).
// out[n,d] = aconst[d] + rsqrt(deg[n]) * sum_e w_e * vbarh[row_e, d]
__global__ __launch_bounds__(256) void k_gather(
    const int* __restrict__ off, const int* __restrict__ deg,
    const unsigned int* __restrict__ srt, const unsigned short* __restrict__ vbarh,
    const float* __restrict__ aconst, float* __restrict__ out)
{
    const int t = threadIdx.x;
    const int l = t & 63;
    const int h = l >> 5;                             // 0: even edges, 1: odd
    const int c2 = l & 31;                            // channel-pair index
    const int n = blockIdx.x * 4 + (t >> 6);          // grid: 12544 -> 50176
    if (n >= N_NODES) return;                          // whole wave exits together
    const float2 ac = ((const float2*)aconst)[c2];    // L2-hot broadcast
    const int e0 = off[n];
    const int dc = deg[n];
    const int e1 = e0 + dc;
    const unsigned int* vb32 = (const unsigned int*)vbarh;
    float ax = 0.f, ay = 0.f;
    int e = e0 + h;                                   // this half's first edge
    for (; e + 6 < e1; e += 8) {                      // 4 edge-pairs (8 edges)/iter
        unsigned int p0 = srt[e];
        unsigned int p1 = srt[e + 2];
        unsigned int p2 = srt[e + 4];
        unsigned int p3 = srt[e + 6];
        unsigned int v0 = vb32[(p0 >> 16) * 32 + c2];
        unsigned int v1 = vb32[(p1 >> 16) * 32 + c2];
        unsigned int v2 = vb32[(p2 >> 16) * 32 + c2];
        unsigned int v3 = vb32[(p3 >> 16) * 32 + c2];
        float w0 = __uint_as_float(p0 << 16);
        float w1 = __uint_as_float(p1 << 16);
        float w2 = __uint_as_float(p2 << 16);
        float w3 = __uint_as_float(p3 << 16);
        ax += (w0 * __uint_as_float(v0 << 16) + w1 * __uint_as_float(v1 << 16))
            + (w2 * __uint_as_float(v2 << 16) + w3 * __uint_as_float(v3 << 16));
        ay += (w0 * __uint_as_float(v0 & 0xFFFF0000u) + w1 * __uint_as_float(v1 & 0xFFFF0000u))
            + (w2 * __uint_as_float(v2 & 0xFFFF0000u) + w3 * __uint_as_float(v3 & 0xFFFF0000u));
    }
    for (; e < e1; e += 2) {                          // remainder, stride 2
        unsigned int p = srt[e];
        unsigned int v = vb32[(p >> 16) * 32 + c2];
        float w = __uint_as_float(p << 16);
        ax += w * __uint_as_float(v << 16);
        ay += w * __uint_as_float(v & 0xFFFF0000u);
    }
    // combine even-edge and odd-edge halves (lanes l and l^32 share channels)
    ax += __shfl_xor(ax, 32, 64);
    ay += __shfl_xor(ay, 32, 64);
    if (h == 0) {
        float dcf = (float)dc;
        float scn = (dcf > 0.f) ? __frsqrt_rn(dcf) : 0.f;
        float2 o;
        o.x = ax * scn + ac.x;
        o.y = ay * scn + ac.y;
        ((float2*)out)[n * 32 + c2] = o;              // coalesced 256 B/row
    }
}

extern "C" void kernel_launch(void* const* d_in, const int* in_sizes, int n_in,
                              void* d_out, int out_size, void* d_ws, size_t ws_size,
                              hipStream_t stream)
{
    const float* Xs = (const float*)d_in[1];   // source_input [N,256]
    const float* Wv = (const float*)d_in[6];   // Wv_w [256,256]
    const float* bv = (const float*)d_in[7];   // Wv_b [256]
    const int*   ei = (const int*)d_in[8];     // edge_index [2,E]
    const float* ew = (const float*)d_in[9];   // edge_weight [E]
    float* out = (float*)d_out;                // [N,64]

    unsigned short* vbarh = (unsigned short*)d_ws;               // 6.4 MB
    uint2* bkt  = (uint2*)(vbarh + (size_t)N_NODES * 64);        // 8.39 MB
    unsigned int* srt = (unsigned int*)(bkt + (size_t)NBUK * BCAP); // 4.19 MB
    unsigned short* wvbar = (unsigned short*)(srt + (size_t)NBUK * BCAP); // 32 KB
    float* bvbar   = (float*)(wvbar + 16384);                    // 64
    float* vsumr   = bvbar + 64;                                 // 32 x 64 replicas
    float* aconst  = vsumr + NVS * 64;                           // 64
    int*   ticket  = (int*)(aconst + 64);                        // 1
    int*   gcur    = ticket + 1;                                 // 512
    int*   deg     = gcur + NBUK;                                // 50,000
    int*   off     = deg + N_NODES;                              // 50,000

    k_wprep<<<16, 256, 0, stream>>>(Wv, bv, wvbar, bvbar, gcur, vsumr, ticket);
    k_part<<<PBLK, 256, 0, stream>>>(ei, ew, gcur, bkt);
    k_bucket<<<NBUK, 256, 0, stream>>>(gcur, bkt, deg, off, srt);
    k_vbar<<<VBLK, 256, 0, stream>>>(Xs, wvbar, bvbar, deg, vbarh, vsumr, ticket, aconst);
    k_gather<<<12544, 256, 0, stream>>>(off, deg, srt, vbarh, aconst, out);
}